// Round 12
// baseline (476.196 us; speedup 1.0000x reference)
//
#include <hip/hip_runtime.h>
#include <hip/hip_bf16.h>
#include <math.h>

#define Nn 8192
#define Dd 256
#define Uu 128
#define MI 16
#define NJC 16                 // j-chunks (one per block column)
#define JCL (Nn / NJC)         // 512 j per block
#define NIT (JCL / 16)         // 32 iterations of 16 j

typedef __attribute__((ext_vector_type(4))) float f32x4;
typedef __attribute__((ext_vector_type(8))) short s16x8;
typedef __attribute__((ext_vector_type(4))) short s16x4;

#define MFMA_K32(a, b, c) __builtin_amdgcn_mfma_f32_16x16x32_bf16((a), (b), (c), 0, 0, 0)

// direct-to-LDS 16B/lane copy: LDS dest = uniform base + lane*16, source per-lane
#define GL_LDS(src, dst)                                                              \
  __builtin_amdgcn_global_load_lds(                                                   \
      (const __attribute__((address_space(1))) unsigned int*)(src),                   \
      (__attribute__((address_space(3))) unsigned int*)(dst), 16, 0, 0)

// K=16 bf16 MFMA: C layout (col=l15,row=4q4+r) of the S^T MFMA == B-frag layout
// (col=l15,k=4q4+e) of this op -> P goes register-direct from S to PV.
__device__ __forceinline__ f32x4 mfma_k16(s16x4 a, s16x4 b, f32x4 c){
#if __has_builtin(__builtin_amdgcn_mfma_f32_16x16x16bf16_1k)
  return __builtin_amdgcn_mfma_f32_16x16x16bf16_1k(a, b, c, 0, 0, 0);
#else
  asm("v_mfma_f32_16x16x16_bf16 %0, %1, %2, %0" : "+v"(c) : "v"(a), "v"(b));
  return c;
#endif
}

__device__ __forceinline__ short f2bf(float f){
  unsigned int u = __float_as_uint(f);
  u += 0x7fffu + ((u >> 16) & 1u);           // RNE
  return (short)(u >> 16);
}

__device__ __forceinline__ float waveSum(float v){
  #pragma unroll
  for (int off = 32; off >= 1; off >>= 1) v += __shfl_xor(v, off);
  return v;
}

// x = expmap0(features @ kernel) -> xh (bf16 [N][U]), x2 = tanh(|z|)^2,
// v4 (V tiles in uc-granular LDS order [jb][uc][q4w][l15][e]);
// 256 threads: half-block g owns 8 rows -> serial FMA chain halved, 8 waves/CU.
__global__ __launch_bounds__(256) void k_prep(const float* __restrict__ feat,
                                              const float* __restrict__ kern,
                                              const float* __restrict__ bias,
                                              short* __restrict__ xh,
                                              short* __restrict__ v4,
                                              float* __restrict__ x2,
                                              float* __restrict__ bb){
  const int t = threadIdx.x;
  const int u = t & 127;                      // output column
  const int g = t >> 7;                       // row-half 0/1
  const int n0 = blockIdx.x * 16;
  __shared__ float fS[16][Dd];
  __shared__ float red[4][8];
  __shared__ float redb[4];
  {
    const f32x4* fg = (const f32x4*)(feat + (size_t)n0 * Dd);
    f32x4* fd = (f32x4*)fS;
    #pragma unroll
    for (int c = 0; c < 4; ++c) fd[c * 256 + t] = fg[c * 256 + t];
  }
  __syncthreads();
  float zz[8];
  #pragma unroll
  for (int r = 0; r < 8; ++r) zz[r] = 0.f;
  for (int dq = 0; dq < 64; ++dq){
    const int d = dq * 4;
    const float k0 = kern[(size_t)(d + 0) * Uu + u];
    const float k1 = kern[(size_t)(d + 1) * Uu + u];
    const float k2 = kern[(size_t)(d + 2) * Uu + u];
    const float k3 = kern[(size_t)(d + 3) * Uu + u];
    #pragma unroll
    for (int r = 0; r < 8; ++r){
      const f32x4 f4 = *(const f32x4*)&fS[g * 8 + r][d];
      zz[r] = fmaf(f4.x, k0, fmaf(f4.y, k1, fmaf(f4.z, k2, fmaf(f4.w, k3, zz[r]))));
    }
  }
  // waves 0,1 hold g=0 (rows 0-7); waves 2,3 hold g=1 (rows 8-15)
  #pragma unroll
  for (int r = 0; r < 8; ++r){
    float v = waveSum(zz[r] * zz[r]);
    if ((t & 63) == 0) red[t >> 6][r] = v;
  }
  __syncthreads();
  float scl[8];
  #pragma unroll
  for (int r = 0; r < 8; ++r){
    const float ns  = (g == 0) ? (red[0][r] + red[1][r]) : (red[2][r] + red[3][r]);
    const float nrm = fmaxf(sqrtf(ns), 1e-15f);
    const float th  = tanhf(nrm);
    scl[r] = th / nrm;
    xh[(size_t)(n0 + g * 8 + r) * Uu + u] = f2bf(zz[r] * scl[r]);
  }
  // v4 element (u, jw=4*q4w+e) at short-offset uc*256 + q4w*64 + l15*4 + e;
  // this thread owns jw = g*8 .. g*8+7 -> q4w = 2g + {0,1}
  {
    short* vt = v4 + (size_t)blockIdx.x * 2048 + (size_t)(u >> 4) * 256 + (u & 15) * 4;
    #pragma unroll
    for (int qq = 0; qq < 2; ++qq){
      s16x4 w;
      #pragma unroll
      for (int e = 0; e < 4; ++e) w[e] = f2bf(zz[qq * 4 + e] * scl[qq * 4 + e]);
      *(s16x4*)(vt + (g * 2 + qq) * 64) = w;
    }
  }
  if (t < 16){
    const float ns  = (t < 8) ? (red[0][t] + red[1][t]) : (red[2][t - 8] + red[3][t - 8]);
    const float nrm = fmaxf(sqrtf(ns), 1e-15f);
    const float th  = tanhf(nrm);
    x2[n0 + t] = th * th;
  }
  if (blockIdx.x == 0){
    const float bv = (t < 128) ? bias[t] : 0.f;
    float v = waveSum(bv * bv);
    if ((t & 63) == 0) redb[t >> 6] = v;
    __syncthreads();
    const float n2  = redb[0] + redb[1] + redb[2] + redb[3];
    const float nrm = fmaxf(sqrtf(n2), 1e-15f);
    const float th  = tanhf(nrm);
    if (t < 128) bb[t] = bv * th / nrm;
    if (t == 0) bb[Uu] = th * th;
  }
}

// LDS-shared attention, 32-i waves + REGISTER DIET for 3 blocks/CU:
// the 32-VGPR adj register queue moves to LDS (global_load_lds lane-addressed
// 16B chunks land exactly as the int4 the p-math consumes; one ds_read_b128 per
// group reads it back). TJ=16 keeps the transient set small. VGPR ~96 fixed
// (oc+qf) + ~60 transients < 170 cap of launch_bounds(256,3) -> 12 waves/CU
// (was 8): the third independent wave per SIMD hides ds_read/MFMA/trans latency
// that R7-R11 scheduling could not. Spill-proof sync (R6 form): all 4 stages
// issued at iter start (full-iter slack > HBM latency), vmcnt(0)+barrier.
__global__ __launch_bounds__(256, 3) void k_attn(const int* __restrict__ adj,
                                                 const short* __restrict__ xh,
                                                 const short* __restrict__ v4,
                                                 const float* __restrict__ x2g,
                                                 float* __restrict__ Opart,
                                                 float* __restrict__ lpart){
  const int t    = threadIdx.x;
  const int lane = t & 63;
  const int wid  = t >> 6;
  const int l15  = lane & 15;
  const int q4   = lane >> 4;
  const int ig   = blockIdx.x >> 4;           // 64 i-groups of 128 rows
  const int jc   = blockIdx.x & 15;           // j-chunk shared by the 4 waves
  const int i0   = ig * 128 + wid * 32;       // this wave: rows i0 .. i0+31
  const int jbase = jc * JCL;

  __shared__ __align__(16) short kb[2][2048];   // K tile, frag layout (4 KB each)
  __shared__ __align__(16) short vb[2][2048];   // V tile, uc layout (4 KB each)
  __shared__ __align__(16) int   ab[2][2048];   // adj tile [wid][g][lane*16B] (8 KB each)
  __shared__ __align__(16) float x2S[JCL];      // x2 chunk (2 KB), staged once

  // staging sources (wave wid stages fragment-chunk kk=wid of K, quarter wid of V,
  // and its OWN adj rows for both groups)
  const char* ksrc = (const char*)xh + (size_t)jbase * 256
                     + l15 * 256 + wid * 64 + q4 * 16;
  const char* vsrc = (const char*)v4 + (size_t)jbase * 256 + wid * 1024 + lane * 16;
  const char* asrc0 = (const char*)(adj + (size_t)(i0 + l15) * Nn + jbase + q4 * 4);
  const char* asrc1 = (const char*)(adj + (size_t)(i0 + 16 + l15) * Nn + jbase + q4 * 4);

  // stage tile 0 + x2 chunk
  GL_LDS(ksrc,  (char*)&kb[0][0] + wid * 1024);
  GL_LDS(vsrc,  (char*)&vb[0][0] + wid * 1024);
  GL_LDS(asrc0, (char*)&ab[0][0] + wid * 2048);
  GL_LDS(asrc1, (char*)&ab[0][0] + wid * 2048 + 1024);
  if (wid < 2)
    GL_LDS((const char*)(x2g + jbase) + wid * 1024 + lane * 16, (char*)x2S + wid * 1024);

  // Q B-frags for both 16-row groups, resident all kernel
  s16x8 qf[2][4];
  float x2i[2], Bv2j[2], nBv2[2];
  int   itDiag[2];
  #pragma unroll
  for (int g = 0; g < 2; ++g){
    const int irow = i0 + g * 16 + l15;
    const short* qp = xh + (size_t)irow * Uu + q4 * 8;
    #pragma unroll
    for (int kk = 0; kk < 4; ++kk) qf[g][kk] = *(const s16x8*)(qp + kk * 32);
    const float xi = x2g[irow];
    x2i[g]  = xi;
    const float Bv = 1.f - xi;
    Bv2j[g] = Bv * Bv;
    nBv2[g] = -2.f * Bv;
    const int i0g = i0 + g * 16;
    itDiag[g] = ((i0g >> 9) == jc) ? ((i0g & 511) >> 4) : -1;
  }

  f32x4 oc[2][8];
  #pragma unroll
  for (int g = 0; g < 2; ++g)
    #pragma unroll
    for (int uc = 0; uc < 8; ++uc) oc[g][uc] = (f32x4){0.f, 0.f, 0.f, 0.f};
  float lacc[2] = {0.f, 0.f};

  asm volatile("s_waitcnt vmcnt(0)" ::: "memory");
  __builtin_amdgcn_s_barrier();
  __builtin_amdgcn_sched_barrier(0);

  #pragma unroll 1
  for (int it = 0; it < NIT; ++it){
    const int cur = it & 1;
    // ---- stage tile it+1 (4 gl_lds, issued first: full iteration in flight) ----
    if (it + 1 < NIT){
      const size_t o = (size_t)(it + 1) * 4096;
      const size_t a = (size_t)(it + 1) * 64;   // 16 ints = 64 B per row step
      GL_LDS(ksrc + o,   (char*)&kb[cur ^ 1][0] + wid * 1024);
      GL_LDS(vsrc + o,   (char*)&vb[cur ^ 1][0] + wid * 1024);
      GL_LDS(asrc0 + a,  (char*)&ab[cur ^ 1][0] + wid * 2048);
      GL_LDS(asrc1 + a,  (char*)&ab[cur ^ 1][0] + wid * 2048 + 1024);
    }
    __builtin_amdgcn_sched_barrier(0);

    // ---- K frags: 4x ds_read_b128 -> S^T for BOTH groups (same kf) ----
    s16x8 kf[4];
    #pragma unroll
    for (int kk = 0; kk < 4; ++kk)
      kf[kk] = *(const s16x8*)((const char*)&kb[cur][0] + kk * 1024 + lane * 16);
    f32x4 s0 = {0.f, 0.f, 0.f, 0.f};
    f32x4 s1 = {0.f, 0.f, 0.f, 0.f};
    #pragma unroll
    for (int kk = 0; kk < 4; ++kk){
      s0 = MFMA_K32(kf[kk], qf[0][kk], s0);
      s1 = MFMA_K32(kf[kk], qf[1][kk], s1);
    }

    // ---- V frags + x2 broadcast ----
    s16x4 vf[8];
    #pragma unroll
    for (int uc = 0; uc < 8; ++uc)
      vf[uc] = *(const s16x4*)((const char*)&vb[cur][0] + uc * 512 + lane * 8);
    const f32x4 x2j = *(const f32x4*)&x2S[it * 16 + q4 * 4];

    // ---- per group: adj from LDS, p-math, pack, PV ----
    s16x4 pbg[2];
    #pragma unroll
    for (int g = 0; g < 2; ++g){
      const int4 aq = *(const int4*)((const char*)&ab[cur][0]
                                     + wid * 2048 + g * 1024 + lane * 16);
      const f32x4 sv = g ? s1 : s0;
      const int aarr[4] = {aq.x, aq.y, aq.z, aq.w};
      float pv[4];
      #pragma unroll
      for (int r = 0; r < 4; ++r){
        const float xy  = sv[r];
        const float x2v = x2j[r];
        const float Aa  = fmaf(-2.f, xy, 1.f + x2v);
        const float num = fmaf(Aa * Aa, x2i[g], fmaf(nBv2[g] * Aa, xy, Bv2j[g] * x2v));
        const float den = fmaf(x2i[g], x2v, fmaf(-2.f, xy, 1.f));
        const float sq  = __builtin_amdgcn_sqrtf(fmaxf(num, 0.f));
        const float pd  = fmaxf(den - sq, 1e-30f);
        const float p   = fminf((den + sq) * __builtin_amdgcn_rcpf(pd), 2.0e7f);
        const bool keep = (aarr[r] != 0) && (sq != 0.f);
        pv[r] = keep ? p : 0.f;
      }
      if (it == itDiag[g]){                   // wave-uniform branch
        const int j0 = jbase + it * 16;
        const int irow = i0 + g * 16 + l15;
        #pragma unroll
        for (int r = 0; r < 4; ++r)
          if ((j0 + 4 * q4 + r) == irow) pv[r] = 0.f;
      }
      lacc[g] += (pv[0] + pv[1]) + (pv[2] + pv[3]);
      s16x4 pb;
      #pragma unroll
      for (int r = 0; r < 4; ++r) pb[r] = f2bf(pv[r]);
      pbg[g] = pb;
    }

    // PV: same vf A-operand feeds both groups
    #pragma unroll
    for (int uc = 0; uc < 8; ++uc){
      oc[0][uc] = mfma_k16(vf[uc], pbg[0], oc[0][uc]);
      oc[1][uc] = mfma_k16(vf[uc], pbg[1], oc[1][uc]);
    }

    // spill-proof drain: stages issued at iter start have landed; barrier flips buf
    asm volatile("s_waitcnt vmcnt(0)" ::: "memory");
    __builtin_amdgcn_s_barrier();
    __builtin_amdgcn_sched_barrier(0);
  }

  // ---- epilogue: reduce l over q4, store per-chunk partials (no atomics) ----
  #pragma unroll
  for (int g = 0; g < 2; ++g){
    float la = lacc[g];
    la += __shfl_xor(la, 16);
    la += __shfl_xor(la, 32);
    if (lane < 16) lpart[(size_t)jc * Nn + i0 + g * 16 + lane] = la;
    float* op = Opart + ((size_t)jc * Nn + i0 + g * 16 + l15) * Uu + q4 * 4;
    #pragma unroll
    for (int uc = 0; uc < 8; ++uc) *(f32x4*)(op + uc * 16) = oc[g][uc];
  }
}

// epilogue: sum 16 partials, normalize, mobius matvec rescale, mobius bias add
__global__ __launch_bounds__(256) void k_out(const float* __restrict__ Opart,
                                             const float* __restrict__ lpart,
                                             const float* __restrict__ x2g,
                                             const float* __restrict__ bb,
                                             float* __restrict__ out){
  const int t  = threadIdx.x;
  const int i0 = blockIdx.x * MI;
  const int er = t >> 4;
  const int ec = t & 15;
  float l = 0.f;
  #pragma unroll
  for (int c = 0; c < NJC; ++c) l += lpart[(size_t)c * Nn + i0 + er];
  const float linv = 1.f / fmaxf(l, 1e-30f);
  float mx[8]; float s2 = 0.f;
  #pragma unroll
  for (int k = 0; k < 8; ++k){
    float v = 0.f;
    #pragma unroll
    for (int c = 0; c < NJC; ++c)
      v += Opart[((size_t)c * Nn + i0 + er) * Uu + ec + 16 * k];
    v *= linv;
    mx[k] = v; s2 = fmaf(v, v, s2);
  }
  s2 += __shfl_xor(s2, 1); s2 += __shfl_xor(s2, 2);
  s2 += __shfl_xor(s2, 4); s2 += __shfl_xor(s2, 8);
  const float mx_n = fmaxf(sqrtf(s2), 1e-15f);
  const float x2e  = x2g[i0 + er];
  const float x_n  = fmaxf(sqrtf(x2e), 1e-15f);
  const float xcl  = fminf(x_n, 1.f - 1e-7f);
  const float art  = 0.5f * __logf((1.f + xcl) / (1.f - xcl));
  const float th   = tanhf(mx_n / x_n * art);
  const float rmn  = th / mx_n;
  float o[8], bu[8]; float ob = 0.f;
  #pragma unroll
  for (int k = 0; k < 8; ++k){
    bu[k] = bb[ec + 16 * k];
    o[k]  = mx[k] * rmn;
    ob = fmaf(o[k], bu[k], ob);
  }
  ob += __shfl_xor(ob, 1); ob += __shfl_xor(ob, 2);
  ob += __shfl_xor(ob, 4); ob += __shfl_xor(ob, 8);
  const float o2   = th * th;
  const float b2   = bb[Uu];
  const float cnum = 1.f + 2.f * ob + b2;
  const float cden = fmaf(o2, b2, 1.f + 2.f * ob);
  const float rden = 1.f / fmaxf(cden, 1e-15f);
  const float co   = 1.f - o2;
  #pragma unroll
  for (int k = 0; k < 8; ++k)
    out[(size_t)(i0 + er) * Uu + ec + 16 * k] = (cnum * o[k] + co * bu[k]) * rden;
}

extern "C" void kernel_launch(void* const* d_in, const int* in_sizes, int n_in,
                              void* d_out, int out_size, void* d_ws, size_t ws_size,
                              hipStream_t stream){
  (void)in_sizes; (void)n_in; (void)out_size; (void)ws_size;
  const float* feat = (const float*)d_in[0];
  const int*   adj  = (const int*)d_in[1];
  const float* kern = (const float*)d_in[2];
  const float* bias = (const float*)d_in[3];

  float* Opart = (float*)d_ws;                          // [16][N][U] f32, 64 MB
  float* lpart = Opart + (size_t)NJC * Nn * Uu;         // [16][N]
  float* x2    = lpart + (size_t)NJC * Nn;              // [N]
  float* bbw   = x2 + Nn;                               // [U+1] (padded to 132)
  short* xh    = (short*)(bbw + 132);                   // [N][U] bf16, 2 MB
  short* v4    = xh + (size_t)Nn * Uu;                  // [N/16][2048] bf16, 2 MB

  k_prep<<<Nn / 16, 256, 0, stream>>>(feat, kern, bias, xh, v4, x2, bbw);
  k_attn<<<(Nn / 128) * NJC, 256, 0, stream>>>(adj, xh, v4, x2, Opart, lpart);
  k_out <<<Nn / MI, 256, 0, stream>>>(Opart, lpart, x2, bbw, (float*)d_out);
}